// Round 9
// baseline (216.437 us; speedup 1.0000x reference)
//
#include <hip/hip_runtime.h>
#include <math.h>

// Problem constants (setup_inputs: bs=16, nq=550, nc=91, nt=48, group_num=11)
#define BS 16
#define NQ 550
#define NC 91
#define NT 48
#define GN 11
#define GQ 50                 // queries per group
#define NTOT (BS * NT)        // 768
#define NROW 48               // LSA rows (targets) after reference transpose
#define MCOL 50               // LSA cols (queries)
#define NPAIR (GN * NT)       // 528
#define NLSA (BS * GN)        // 176 LSA blocks

// ---------------- focal (class) cost: fast f32 (R4/R6-proven) ---------------
__device__ __forceinline__ float focal_cost_f32(float x) {
    float prob = 1.0f / (1.0f + __expf(-x));
    float q = 1.0f - prob;
    float lneg = __logf(q + 1e-8f);
    float lpos = __logf(prob + 1e-8f);
    float neg = 0.75f * (prob * prob) * (-lneg);
    float pos = 0.25f * (q * q) * (-lpos);
    return pos - neg;
}

// ---------------- one C element, f32 __f*_rn box math ------------------------
__device__ __forceinline__ float cost_element(
    const float* __restrict__ logits,
    const float* __restrict__ pboxes, const int* __restrict__ labels,
    const float* __restrict__ tboxes, int p, int t)
{
    const float* pb = pboxes + (long)p * 6;
    float pcx = pb[0], pcy = pb[1], pl = pb[2], pr = pb[3], ptt = pb[4], pbo = pb[5];
    const float* tb = tboxes + (long)t * 6;
    float tcx = tb[0], tcy = tb[1], tl = tb[2], tr = tb[3], ttt = tb[4], tbo = tb[5];

    float c3d = __fadd_rn(fabsf(__fsub_rn(pcx, tcx)), fabsf(__fsub_rn(pcy, tcy)));
    float cbb = __fadd_rn(
                  __fadd_rn(
                    __fadd_rn(fabsf(__fsub_rn(pl, tl)), fabsf(__fsub_rn(pr, tr))),
                    fabsf(__fsub_rn(ptt, ttt))),
                  fabsf(__fsub_rn(pbo, tbo)));

    float px1 = __fsub_rn(pcx, pl), py1 = __fsub_rn(pcy, ptt);
    float px2 = __fadd_rn(pcx, pr), py2 = __fadd_rn(pcy, pbo);
    float tx1 = __fsub_rn(tcx, tl), ty1 = __fsub_rn(tcy, ttt);
    float tx2 = __fadd_rn(tcx, tr), ty2 = __fadd_rn(tcy, tbo);

    float area1 = __fmul_rn(__fsub_rn(px2, px1), __fsub_rn(py2, py1));
    float area2 = __fmul_rn(__fsub_rn(tx2, tx1), __fsub_rn(ty2, ty1));
    float ltx = fmaxf(px1, tx1), lty = fmaxf(py1, ty1);
    float rbx = fminf(px2, tx2), rby = fminf(py2, ty2);
    float wx = fmaxf(__fsub_rn(rbx, ltx), 0.0f);
    float wy = fmaxf(__fsub_rn(rby, lty), 0.0f);
    float inter = __fmul_rn(wx, wy);
    float uni = __fsub_rn(__fadd_rn(area1, area2), inter);
    float iou = __fdiv_rn(inter, uni);
    float ex1 = fminf(px1, tx1), ey1 = fminf(py1, ty1);
    float ex2 = fmaxf(px2, tx2), ey2 = fmaxf(py2, ty2);
    float ew = fmaxf(__fsub_rn(ex2, ex1), 0.0f);
    float eh = fmaxf(__fsub_rn(ey2, ey1), 0.0f);
    float earea = __fmul_rn(ew, eh);
    float giou = __fsub_rn(iou, __fdiv_rn(__fsub_rn(earea, uni), earea));
    float cgiou = -giou;

    float cclass = focal_cost_f32(logits[(long)p * NC + labels[t]]);

    float out = __fmul_rn(5.0f, cbb);
    out = __fadd_rn(out, __fmul_rn(10.0f, c3d));
    out = __fadd_rn(out, __fmul_rn(2.0f, cclass));
    out = __fadd_rn(out, __fmul_rn(2.0f, cgiou));
    return out;
}

// ---------------- cross-lane helpers ----------------------------------------
__device__ __forceinline__ double readlane_f64(double x, int l) {
    long long b = __double_as_longlong(x);
    int lo = __builtin_amdgcn_readlane((int)(b & 0xffffffffLL), l);
    int hi = __builtin_amdgcn_readlane((int)(b >> 32), l);
    return __longlong_as_double(((long long)hi << 32) | (unsigned int)lo);
}

// order-preserving f32 -> u32 map: a < b (float, no NaN) <=> fkey(a) < fkey(b).
// Bijective, so u32-key equality == f32 bit equality; winner set identical to
// R2's float compare (difference only at +0/-0 ties: measure-zero here).
__device__ __forceinline__ unsigned fkey_u32(float f) {
    unsigned b = __float_as_uint(f);
    return b ^ (unsigned)(((int)b >> 31) | 0x80000000);
}

// one within-row-of-16 DPP u32-min stage
template <int CTRL>
__device__ __forceinline__ unsigned dpp_min_u32(unsigned x) {
    unsigned t = (unsigned)__builtin_amdgcn_update_dpp((int)x, (int)x, CTRL, 0xf, 0xf, false);
    return (x < t) ? x : t;
}

// 4-stage within-row reduce + 4 readlanes + SALU tree (R8-proven argmin core)
#define WAVE_MIN_U32(ukey, kmin_out)                                          \
    {                                                                         \
        unsigned red_ = (ukey);                                               \
        red_ = dpp_min_u32<0x111>(red_);                                      \
        red_ = dpp_min_u32<0x112>(red_);                                      \
        red_ = dpp_min_u32<0x114>(red_);                                      \
        red_ = dpp_min_u32<0x118>(red_);                                      \
        unsigned a_ = (unsigned)__builtin_amdgcn_readlane((int)red_, 15);     \
        unsigned b_ = (unsigned)__builtin_amdgcn_readlane((int)red_, 31);     \
        unsigned c_ = (unsigned)__builtin_amdgcn_readlane((int)red_, 47);     \
        unsigned d_ = (unsigned)__builtin_amdgcn_readlane((int)red_, 63);     \
        unsigned e_ = (a_ < b_) ? a_ : b_;                                    \
        unsigned f_ = (c_ < d_) ? c_ : d_;                                    \
        (kmin_out) = (e_ < f_) ? e_ : f_;                                     \
    }

// ---------------- mega kernel: blocks [0,176) = LSA, rest = cost matrix -----
// R9 = R8 (verified 100.6 us) + load-latency speculation. The trajectory is
// BIT-IDENTICAL to R8: only WHICH ds_reads are issued and WHEN changes; the
// value consumed for row r is always lcost[r][cidx] (same address -> same
// bits), selected by a wave-uniform compare of the true row index.
//   - In the load shadow (after the f64 dual updates), a second u32-key
//     reduce over the post-update kprev (free lanes minus j1) PREDICTS the
//     next iteration's argmin lane; its pcol gives the row consumed two
//     iterations out, and its load is issued immediately (~1 full iteration
//     of flight time -> latency fully hidden on hit).
//   - On resolution, hit: use the in-flight value. Miss: issue the true row
//     load exactly as R8 did (no loss; the spec reduce filled stall cycles).
//   - Phase-boundary prefetch: phase i+1's first row (= i) is deterministic;
//     its load issues before the back-walk and hides under it.
// Hit rate is highest in LONG phases (minv = min over many rows -> a new row
// rarely beats the standing runner-up) -- exactly where the time is spent.
__global__ __launch_bounds__(256) void mega_kernel(
    const float* __restrict__ logits,
    const float* __restrict__ pboxes,
    const int*   __restrict__ labels,
    const float* __restrict__ tboxes,
    float*       __restrict__ C,
    float*       __restrict__ pi,
    float*       __restrict__ ti)
{
    if (blockIdx.x >= NLSA) {
        long idx = (long)(blockIdx.x - NLSA) * 256 + threadIdx.x;
        if (idx >= (long)BS * NQ * NTOT) return;
        int t = (int)(idx % NTOT);
        int p = (int)(idx / NTOT);
        C[idx] = cost_element(logits, pboxes, labels, tboxes, p, t);
        return;
    }

    // ---- LSA block ----
    const int blk = blockIdx.x;          // 0..175
    const int b = blk / GN, g = blk % GN;
    const int tid = threadIdx.x;

    __shared__ double lcost[NROW * MCOL];   // [row i][col j]

    // All 256 threads fill the 48x50 tile, then waves 1-3 exit.
    for (int k = tid; k < NROW * MCOL; k += 256) {
        int i = k % NROW, j = k / NROW;
        float cf = cost_element(logits, pboxes, labels, tboxes,
                                b * NQ + g * GQ + j, b * NT + i);
        lcost[i * MCOL + j] = (double)cf;
    }
    __syncthreads();
    if (tid >= 64) return;

    const int lane = tid;
    const bool incol = (lane >= 1 && lane <= MCOL);
    const int cidx = incol ? lane - 1 : 0;
    const double INF = __builtin_inf();
    const float INFF = __builtin_inff();

    int    pcol_l = 0;    // p[lane]   (0 = unassigned)
    double urow_l = 0.0;  // u[p[lane]]
    double v_l    = 0.0;  // v[lane]
    int    way_l  = 0;
    double minv_l = INF;
    float  kprev  = INFF; // f32 image of minv_l (monotone)
    bool   used_l = false;

    // phase-boundary prefetch: row 0 for phase i=1
    double cd_phase = lcost[0 * MCOL + cidx];

    for (int i = 1; i <= NROW; ++i) {
        if (lane == 0) { pcol_l = i; urow_l = 0.0; }  // p[0]=i, u[i]=0
        minv_l = INF;
        kprev  = INFF;
        used_l = false;
        int j0 = 0;
        int i0 = i;            // p[j0], wave-uniform
        double u_i0 = 0.0;     // u[i0]
        double cd = cd_phase;  // prefetched during previous back-walk

        int    spec_row = -1;  // predicted next-next row (wave-uniform)
        double spec_val = 0.0; // its in-flight value

        for (int guard = 0; guard <= MCOL + 1; ++guard) {
            used_l = used_l || (lane == j0);
            bool freel = incol && !used_l;

            double cur = (cd - u_i0) - v_l;           // (cost - u) - v, ref order
            bool upd   = freel && (cur < minv_l);
            minv_l = upd ? cur : minv_l;
            way_l  = upd ? j0  : way_l;

            // f32 key: exact image of updated minv for free lanes, +inf else
            float kf = freel ? fminf(__double2float_rn(cur), kprev) : INFF;
            unsigned ukey = fkey_u32(kf);
            unsigned kmin;
            WAVE_MIN_U32(ukey, kmin);

            unsigned long long mm = __ballot(ukey == kmin);
            int j1 = (int)__builtin_ctzll(mm);        // lowest lane = np.argmin

            int i0n = __builtin_amdgcn_readlane(pcol_l, j1);

            // resolve next row's value ASAP: hit -> in-flight spec load;
            // miss -> issue the true load (clamped; unused when we break).
            int r_true = (i0n > 0) ? (i0n - 1) : 0;
            double cd_next;
            if (i0n > 0 && r_true == spec_row) {
                cd_next = spec_val;                    // same address, same bits
            } else {
                cd_next = lcost[r_true * MCOL + cidx];
            }

            double delta = readlane_f64(minv_l, j1);  // exact f64 min value
            double u_nx  = readlane_f64(urow_l, j1);

            // f64 dual updates (in the load shadow, as in R2/R8)
            urow_l = used_l ? urow_l + delta : urow_l;
            v_l    = used_l ? v_l - delta    : v_l;
            minv_l = freel  ? minv_l - delta : minv_l;
            kprev  = __double2float_rn(minv_l);

            // speculative prefetch for the row after next: argmin of the
            // post-update kprev over (free \ {j1}) predicts the next argmin.
            {
                unsigned us = (freel && lane != j1) ? fkey_u32(kprev)
                                                    : 0xFFFFFFFFu;
                unsigned skmin;
                WAVE_MIN_U32(us, skmin);
                unsigned long long smm = __ballot(us == skmin);
                spec_row = -1;
                if (smm != 0ull) {
                    int sj = (int)__builtin_ctzll(smm);
                    int sp = __builtin_amdgcn_readlane(pcol_l, sj);
                    if (sp > 0) {
                        spec_row = sp - 1;
                        spec_val = lcost[spec_row * MCOL + cidx];
                    }
                }
            }

            j0 = j1;
            if (i0n == 0) break;
            i0   = i0n;
            u_i0 = u_nx;
            cd   = cd_next;
        }

        // phase-boundary prefetch: next phase starts with row (i+1)-1 = i
        if (i < NROW) cd_phase = lcost[i * MCOL + cidx];

        // augment back-walk: p[j]=p[way[j]], moving urow with pcol
        int j = j0;
        while (j != 0) {
            int wj    = __builtin_amdgcn_readlane(way_l, j);
            int pr    = __builtin_amdgcn_readlane(pcol_l, wj);
            double ur = readlane_f64(urow_l, wj);
            if (lane == j) { pcol_l = pr; urow_l = ur; }
            j = wj;
        }
    }

    // Extraction: ascending query (column) order == reference order.
    unsigned long long asg = __ballot(incol && pcol_l != 0);
    if (incol && pcol_l != 0) {
        int k = __popcll(asg & ((1ull << lane) - 1));
        float* pib = pi + ((long)b * NPAIR + (long)g * NT);
        float* tib = ti + ((long)b * NPAIR + (long)g * NT);
        pib[k] = (float)(g * GQ + cidx);
        tib[k] = (float)(pcol_l - 1);
    }
}

extern "C" void kernel_launch(void* const* d_in, const int* in_sizes, int n_in,
                              void* d_out, int out_size, void* d_ws, size_t ws_size,
                              hipStream_t stream) {
    const float* logits = (const float*)d_in[0];   // [16,550,91] f32
    const float* pboxes = (const float*)d_in[1];   // [16,550,6] f32
    const int*   labels = (const int*)d_in[2];     // [16,48] i32
    const float* tboxes = (const float*)d_in[3];   // [16,48,6] f32

    float* out = (float*)d_out;
    float* C  = out;                               // 16*550*768
    float* pi = out + (long)BS * NQ * NTOT;
    float* ti = pi + (long)BS * NPAIR;

    long total = (long)BS * NQ * NTOT;
    int cost_blocks = (int)((total + 255) / 256);
    int mega_blocks = NLSA + cost_blocks;

    mega_kernel<<<mega_blocks, 256, 0, stream>>>(
        logits, pboxes, labels, tboxes, C, pi, ti);
}

// Round 10
// 159.950 us; speedup vs baseline: 1.3532x; 1.3532x over previous
//
#include <hip/hip_runtime.h>
#include <math.h>

// Problem constants (setup_inputs: bs=16, nq=550, nc=91, nt=48, group_num=11)
#define BS 16
#define NQ 550
#define NC 91
#define NT 48
#define GN 11
#define GQ 50                 // queries per group
#define NTOT (BS * NT)        // 768
#define NROW 48               // LSA rows (targets) after reference transpose
#define MCOL 50               // LSA cols (queries)
#define NPAIR (GN * NT)       // 528
#define NLSA (BS * GN)        // 176 LSA blocks

// ---------------- focal (class) cost: fast f32 (R4/R6-proven) ---------------
__device__ __forceinline__ float focal_cost_f32(float x) {
    float prob = 1.0f / (1.0f + __expf(-x));
    float q = 1.0f - prob;
    float lneg = __logf(q + 1e-8f);
    float lpos = __logf(prob + 1e-8f);
    float neg = 0.75f * (prob * prob) * (-lneg);
    float pos = 0.25f * (q * q) * (-lpos);
    return pos - neg;
}

// ---------------- one C element, f32 __f*_rn box math ------------------------
__device__ __forceinline__ float cost_element(
    const float* __restrict__ logits,
    const float* __restrict__ pboxes, const int* __restrict__ labels,
    const float* __restrict__ tboxes, int p, int t)
{
    const float* pb = pboxes + (long)p * 6;
    float pcx = pb[0], pcy = pb[1], pl = pb[2], pr = pb[3], ptt = pb[4], pbo = pb[5];
    const float* tb = tboxes + (long)t * 6;
    float tcx = tb[0], tcy = tb[1], tl = tb[2], tr = tb[3], ttt = tb[4], tbo = tb[5];

    float c3d = __fadd_rn(fabsf(__fsub_rn(pcx, tcx)), fabsf(__fsub_rn(pcy, tcy)));
    float cbb = __fadd_rn(
                  __fadd_rn(
                    __fadd_rn(fabsf(__fsub_rn(pl, tl)), fabsf(__fsub_rn(pr, tr))),
                    fabsf(__fsub_rn(ptt, ttt))),
                  fabsf(__fsub_rn(pbo, tbo)));

    float px1 = __fsub_rn(pcx, pl), py1 = __fsub_rn(pcy, ptt);
    float px2 = __fadd_rn(pcx, pr), py2 = __fadd_rn(pcy, pbo);
    float tx1 = __fsub_rn(tcx, tl), ty1 = __fsub_rn(tcy, ttt);
    float tx2 = __fadd_rn(tcx, tr), ty2 = __fadd_rn(tcy, tbo);

    float area1 = __fmul_rn(__fsub_rn(px2, px1), __fsub_rn(py2, py1));
    float area2 = __fmul_rn(__fsub_rn(tx2, tx1), __fsub_rn(ty2, ty1));
    float ltx = fmaxf(px1, tx1), lty = fmaxf(py1, ty1);
    float rbx = fminf(px2, tx2), rby = fminf(py2, ty2);
    float wx = fmaxf(__fsub_rn(rbx, ltx), 0.0f);
    float wy = fmaxf(__fsub_rn(rby, lty), 0.0f);
    float inter = __fmul_rn(wx, wy);
    float uni = __fsub_rn(__fadd_rn(area1, area2), inter);
    float iou = __fdiv_rn(inter, uni);
    float ex1 = fminf(px1, tx1), ey1 = fminf(py1, ty1);
    float ex2 = fmaxf(px2, tx2), ey2 = fmaxf(py2, ty2);
    float ew = fmaxf(__fsub_rn(ex2, ex1), 0.0f);
    float eh = fmaxf(__fsub_rn(ey2, ey1), 0.0f);
    float earea = __fmul_rn(ew, eh);
    float giou = __fsub_rn(iou, __fdiv_rn(__fsub_rn(earea, uni), earea));
    float cgiou = -giou;

    float cclass = focal_cost_f32(logits[(long)p * NC + labels[t]]);

    float out = __fmul_rn(5.0f, cbb);
    out = __fadd_rn(out, __fmul_rn(10.0f, c3d));
    out = __fadd_rn(out, __fmul_rn(2.0f, cclass));
    out = __fadd_rn(out, __fmul_rn(2.0f, cgiou));
    return out;
}

// ---------------- cross-lane helpers ----------------------------------------
__device__ __forceinline__ double readlane_f64(double x, int l) {
    long long b = __double_as_longlong(x);
    int lo = __builtin_amdgcn_readlane((int)(b & 0xffffffffLL), l);
    int hi = __builtin_amdgcn_readlane((int)(b >> 32), l);
    return __longlong_as_double(((long long)hi << 32) | (unsigned int)lo);
}

// order-preserving f32 -> u32 map: a < b (float, no NaN) <=> fkey(a) < fkey(b).
// Bijective, so u32-key equality == f32 bit equality; winner set identical to
// R2's float compare (difference only at +0/-0 ties: measure-zero here).
__device__ __forceinline__ unsigned fkey_u32(float f) {
    unsigned b = __float_as_uint(f);
    return b ^ (unsigned)(((int)b >> 31) | 0x80000000);
}

// one within-row-of-16 DPP u32-min stage
template <int CTRL>
__device__ __forceinline__ unsigned dpp_min_u32(unsigned x) {
    unsigned t = (unsigned)__builtin_amdgcn_update_dpp((int)x, (int)x, CTRL, 0xf, 0xf, false);
    return (x < t) ? x : t;
}

// ---------------- mega kernel: blocks [0,176) = LSA, rest = cost matrix -----
// R10 = R8 (verified 100.6 us; u32-key DPP/SALU argmin, exact f64 state,
// speculative next-row ds_read) + ONE change: s_setprio(3) on the solver
// wave. The LSA wave shares its SIMD with up to 7 cost-matrix waves; on a
// latency-bound serial chain every lost issue-arbitration cycle is wall
// time (T5 regime: waves at different phases, one latency-critical).
// Priority is a scheduler hint only -- trajectory identical to R8.
// (R9's speculation reverted: cross-lane ops are exec-path serial time,
// +130 cy/iter. There is no free VALU window in a serial chain.)
__global__ __launch_bounds__(256) void mega_kernel(
    const float* __restrict__ logits,
    const float* __restrict__ pboxes,
    const int*   __restrict__ labels,
    const float* __restrict__ tboxes,
    float*       __restrict__ C,
    float*       __restrict__ pi,
    float*       __restrict__ ti)
{
    if (blockIdx.x >= NLSA) {
        long idx = (long)(blockIdx.x - NLSA) * 256 + threadIdx.x;
        if (idx >= (long)BS * NQ * NTOT) return;
        int t = (int)(idx % NTOT);
        int p = (int)(idx / NTOT);
        C[idx] = cost_element(logits, pboxes, labels, tboxes, p, t);
        return;
    }

    // ---- LSA block ----
    const int blk = blockIdx.x;          // 0..175
    const int b = blk / GN, g = blk % GN;
    const int tid = threadIdx.x;

    __shared__ double lcost[NROW * MCOL];   // [row i][col j]

    // All 256 threads fill the 48x50 tile, then waves 1-3 exit.
    for (int k = tid; k < NROW * MCOL; k += 256) {
        int i = k % NROW, j = k / NROW;
        float cf = cost_element(logits, pboxes, labels, tboxes,
                                b * NQ + g * GQ + j, b * NT + i);
        lcost[i * MCOL + j] = (double)cf;
    }
    __syncthreads();
    if (tid >= 64) return;

    // latency-critical serial solver: outbid co-resident cost-matrix waves
    __builtin_amdgcn_s_setprio(3);

    const int lane = tid;
    const bool incol = (lane >= 1 && lane <= MCOL);
    const int cidx = incol ? lane - 1 : 0;
    const double INF = __builtin_inf();
    const float INFF = __builtin_inff();

    int    pcol_l = 0;    // p[lane]   (0 = unassigned)
    double urow_l = 0.0;  // u[p[lane]]
    double v_l    = 0.0;  // v[lane]
    int    way_l  = 0;
    double minv_l = INF;
    float  kprev  = INFF; // f32 image of minv_l (monotone)
    bool   used_l = false;

    for (int i = 1; i <= NROW; ++i) {
        if (lane == 0) { pcol_l = i; urow_l = 0.0; }  // p[0]=i, u[i]=0
        minv_l = INF;
        kprev  = INFF;
        used_l = false;
        int j0 = 0;
        int i0 = i;            // p[j0], wave-uniform
        double u_i0 = 0.0;     // u[i0]
        double cd = lcost[(i0 - 1) * MCOL + cidx];   // pre-issued row load

        for (int guard = 0; guard <= MCOL + 1; ++guard) {
            used_l = used_l || (lane == j0);
            bool freel = incol && !used_l;

            double cur = (cd - u_i0) - v_l;           // (cost - u) - v, ref order
            bool upd   = freel && (cur < minv_l);
            minv_l = upd ? cur : minv_l;
            way_l  = upd ? j0  : way_l;

            // f32 key: exact image of updated minv for free lanes, +inf else
            // (fminf(cvt(cur), kprev) == cvt(min(cur, minv_old)) by monotonicity)
            float kf = freel ? fminf(__double2float_rn(cur), kprev) : INFF;

            // argmin via u32 key: 4 within-row DPP stages -> row minima at
            // lanes 15/31/47/63 -> readlane x4 -> SALU min tree -> ballot.
            unsigned ukey = fkey_u32(kf);
            unsigned red = ukey;
            red = dpp_min_u32<0x111>(red);  // row_shr:1
            red = dpp_min_u32<0x112>(red);  // row_shr:2
            red = dpp_min_u32<0x114>(red);  // row_shr:4
            red = dpp_min_u32<0x118>(red);  // row_shr:8
            unsigned m0 = (unsigned)__builtin_amdgcn_readlane((int)red, 15);
            unsigned m1 = (unsigned)__builtin_amdgcn_readlane((int)red, 31);
            unsigned m2 = (unsigned)__builtin_amdgcn_readlane((int)red, 47);
            unsigned m3 = (unsigned)__builtin_amdgcn_readlane((int)red, 63);
            unsigned ka = (m0 < m1) ? m0 : m1;
            unsigned kb = (m2 < m3) ? m2 : m3;
            unsigned kmin = (ka < kb) ? ka : kb;

            unsigned long long mm = __ballot(ukey == kmin);
            int j1 = (int)__builtin_ctzll(mm);        // lowest lane = np.argmin

            int    i0n   = __builtin_amdgcn_readlane(pcol_l, j1);
            double delta = readlane_f64(minv_l, j1);  // exact f64 min value
            double u_nx  = readlane_f64(urow_l, j1);

            // speculative next-row load issued before the f64 updates; row
            // clamped so the read is always in-bounds (result unused on break).
            int r_next = (i0n > 0) ? (i0n - 1) : 0;
            double cd_next = lcost[r_next * MCOL + cidx];

            urow_l = used_l ? urow_l + delta : urow_l;
            v_l    = used_l ? v_l - delta    : v_l;
            minv_l = freel  ? minv_l - delta : minv_l;
            kprev  = __double2float_rn(minv_l);

            j0 = j1;
            if (i0n == 0) break;
            i0   = i0n;
            u_i0 = u_nx;
            cd   = cd_next;
        }

        // augment back-walk: p[j]=p[way[j]], moving urow with pcol
        int j = j0;
        while (j != 0) {
            int wj    = __builtin_amdgcn_readlane(way_l, j);
            int pr    = __builtin_amdgcn_readlane(pcol_l, wj);
            double ur = readlane_f64(urow_l, wj);
            if (lane == j) { pcol_l = pr; urow_l = ur; }
            j = wj;
        }
    }

    // Extraction: ascending query (column) order == reference order.
    unsigned long long asg = __ballot(incol && pcol_l != 0);
    if (incol && pcol_l != 0) {
        int k = __popcll(asg & ((1ull << lane) - 1));
        float* pib = pi + ((long)b * NPAIR + (long)g * NT);
        float* tib = ti + ((long)b * NPAIR + (long)g * NT);
        pib[k] = (float)(g * GQ + cidx);
        tib[k] = (float)(pcol_l - 1);
    }
}

extern "C" void kernel_launch(void* const* d_in, const int* in_sizes, int n_in,
                              void* d_out, int out_size, void* d_ws, size_t ws_size,
                              hipStream_t stream) {
    const float* logits = (const float*)d_in[0];   // [16,550,91] f32
    const float* pboxes = (const float*)d_in[1];   // [16,550,6] f32
    const int*   labels = (const int*)d_in[2];     // [16,48] i32
    const float* tboxes = (const float*)d_in[3];   // [16,48,6] f32

    float* out = (float*)d_out;
    float* C  = out;                               // 16*550*768
    float* pi = out + (long)BS * NQ * NTOT;
    float* ti = pi + (long)BS * NPAIR;

    long total = (long)BS * NQ * NTOT;
    int cost_blocks = (int)((total + 255) / 256);
    int mega_blocks = NLSA + cost_blocks;

    mega_kernel<<<mega_blocks, 256, 0, stream>>>(
        logits, pboxes, labels, tboxes, C, pi, ti);
}